// Round 6
// baseline (734.949 us; speedup 1.0000x reference)
//
#include <hip/hip_runtime.h>
#include <math.h>

// SSIM-with-logits fused kernel for MI355X (gfx950). Round 6.
// R4/R5 post-mortem: total regs/wave ~256 (VGPR+AGPR, unified file) hard-caps
// residency at 2 waves/SIMD no matter the grid; the block-wide barrier every
// 11 rows then convoys all 8 waves/CU -> VALUBusy stuck ~51-59%.
// R6: barrier-free wave-autonomous strips. Each WAVE owns a 64-wide x 64-tall
// output strip, stages its own 74-cell rows (sigmoid applied once) into a
// PRIVATE 11-row LDS ring, and shares across lanes wave-synchronously:
//   - zero __syncthreads in the hot loop (one at the final reduction only)
//   - write-ahead distance 2 in the ring; explicit `s_waitcnt lgkmcnt(2)`
//     (+ compiler memory fence) guarantees the distance-2 RAW without ever
//     waiting on the just-issued write
//   - prefetch arrays shrink 44 regs -> 8, so __launch_bounds__(256,4)
//     (128-reg budget) should hold the ~85-float live state spill-free
//     => up to 4 waves/SIMD resident. WRITE_SIZE is the spill canary.

typedef __attribute__((ext_vector_type(2))) float f2;

#define H_IMG 1024
#define W_IMG 1024
#define N_IMG 16
#define PADR 5
#define LDS_ROW 76   // f2 cells per ring row (74 used + pad)
#define NSLOT 11

// Normalized 1D Gaussian, WS=11, sigma=1.5 (absmax 0.0 in R1-R5)
constexpr float GW[11] = {
    0.00102838f, 0.00759877f, 0.03600077f, 0.10936069f, 0.21300553f,
    0.26601172f,
    0.21300553f, 0.10936069f, 0.03600077f, 0.00759877f, 0.00102838f};

__device__ __forceinline__ int reflect_i(int i, int n) {
    i = (i < 0) ? -i : i;
    i = (i >= n) ? (2 * n - 2 - i) : i;
    return i;
}

__device__ __forceinline__ float fast_sigmoid(float x) {
    return __builtin_amdgcn_rcpf(1.0f + __expf(-x));
}

__device__ __forceinline__ void ssim_emit(
    f2 mu, f2 sq, float e12, float& loss_sum)
{
    const float mu1 = mu.x, mu2 = mu.y;
    const float mu1s = mu1 * mu1;
    const float mu2s = mu2 * mu2;
    const float mu12 = mu1 * mu2;
    const float s1  = sq.x - mu1s;
    const float s2  = sq.y - mu2s;
    const float s12 = e12  - mu12;
    const float C1 = 1e-4f, C2 = 9e-4f;
    const float num = (2.0f * mu12 + C1) * (2.0f * s12 + C2);
    const float den = (mu1s + mu2s + C1) * (s1 + s2 + C2);
    float l = 1.0f - num * __builtin_amdgcn_rcpf(den);
    l = fminf(fmaxf(l, 0.0f), 1.0f) * 0.5f;
    loss_sum += l;
}

struct PF { float a0, b0, a1, b1; };  // one prefetched row (main + halo)

// One row of the separable filter; RR = row % 11 (compile-time) so all LDS
// offsets and accumulator slots fold to constants. Mod-11 slot machinery
// validated bit-exact in R2-R5.
template<int RR, bool GUARD>
__device__ __forceinline__ void process_row_t(
    const f2 (*__restrict__ slab)[LDS_ROW], int lane,
    f2 (&vAB)[11], f2 (&vSQ)[11], float (&vX)[11], float& loss_sum)
{
    // ---- horizontal 11-tap of (a,b)/(aa,bb)/ab at column `lane` ----
    f2 hAB = (f2)(0.0f), hSQ = (f2)(0.0f);
    float hab = 0.0f;
#pragma unroll
    for (int k = 0; k < 11; ++k) {
        const f2 v   = slab[RR][lane + k];
        const f2 wa2 = ((f2)(GW[k])) * v;
        hAB += wa2;
        hSQ  = __builtin_elementwise_fma(wa2, v, hSQ);
        hab  = fmaf(wa2.x, v.y, hab);
    }
    // ---- vertical scatter into mod-11 slots ----
#pragma unroll
    for (int j = 0; j < 11; ++j) {
        if (!(GUARD && j > RR)) {
            const int s = (RR - j + 22) % 11;
            const f2 w2 = (f2)(GW[j]);
            vAB[s] = __builtin_elementwise_fma(w2, hAB, vAB[s]);
            vSQ[s] = __builtin_elementwise_fma(w2, hSQ, vSQ[s]);
            vX[s]  = fmaf(GW[j], hab, vX[s]);
        }
    }
    // ---- completion: slot (RR+1)%11 finished an output row ----
    if (!GUARD || RR == 10) {
        const int s = (RR + 1) % 11;
        ssim_emit(vAB[s], vSQ[s], vX[s], loss_sum);
        vAB[s] = (f2)(0.0f); vSQ[s] = (f2)(0.0f); vX[s] = 0.0f;
    }
}

// Unrolled group of NR rows starting at `base` (base % 11 == 0).
// Iteration RR: load row base+RR+3 (if < NLOAD), fence, process slot RR,
// write row base+RR+2 into slot (RR+2)%11 (if < NWRITE).
// Fence: lgkmcnt(2) leaves the previous iteration's 2 ds_writes outstanding
// but guarantees everything older — including the distance-2 write this
// iteration's reads depend on — has completed. DS ops retire in order.
template<int RR, int NR, int NWRITE, int NLOAD, bool GUARD,
         typename LoadF, typename WriteF>
__device__ __forceinline__ void group_iter(
    int base, LoadF& load_row, WriteF& write_row, PF (&pf)[2],
    f2 (*__restrict__ slab)[LDS_ROW], int lane,
    f2 (&vAB)[11], f2 (&vSQ)[11], float (&vX)[11], float& loss_sum)
{
    if constexpr (RR < NR) {
        if constexpr (RR < NLOAD)
            load_row(base + RR + 3, pf[(RR + 1) & 1]);
        asm volatile("s_waitcnt lgkmcnt(2)" ::: "memory");
        process_row_t<RR, GUARD>(slab, lane, vAB, vSQ, vX, loss_sum);
        if constexpr (RR < NWRITE)
            write_row((RR + 2) % 11, pf[RR & 1]);
        group_iter<RR + 1, NR, NWRITE, NLOAD, GUARD>(
            base, load_row, write_row, pf, slab, lane, vAB, vSQ, vX, loss_sum);
    }
}

__global__ __launch_bounds__(256, 4) void ssim_main(
    const float* __restrict__ inp, const float* __restrict__ tgt,
    float* __restrict__ out)
{
    __shared__ f2 lds[4][NSLOT][LDS_ROW];   // per-wave private rings, ~26.8 KB
    __shared__ float red[4];

    const int tid  = threadIdx.x;
    const int lane = tid & 63;
    const int wv   = tid >> 6;
    f2 (*__restrict__ slab)[LDS_ROW] = lds[wv];

    const int task  = blockIdx.x * 4 + wv;  // 4096 wave-tasks
    const int img   = task >> 8;            // 0..15
    const int rem   = task & 255;
    const int strip = rem & 15;             // 16 strips of 64 cols
    const int band  = rem >> 4;             // 16 bands of 64 rows

    const float* __restrict__ A = inp + (size_t)img * (H_IMG * (size_t)W_IMG);
    const float* __restrict__ B = tgt + (size_t)img * (H_IMG * (size_t)W_IMG);

    const int xc      = strip * 64;
    const int y_start = band * 64 - PADR;   // 74 input rows: 6x11 + 8

    // cell c (0..73) <-> col xc-5+c ; lane owns cell `lane`, lanes<10 also 64+lane
    const int c0   = reflect_i(xc - PADR + lane, W_IMG);
    const int c1   = reflect_i(xc + 59 + lane, W_IMG);
    const bool halo = lane < 2 * PADR;

    f2 vAB[11], vSQ[11];
    float vX[11];
#pragma unroll
    for (int j = 0; j < 11; ++j) {
        vAB[j] = (f2)(0.0f); vSQ[j] = (f2)(0.0f); vX[j] = 0.0f;
    }
    float loss_sum = 0.0f;
    PF pf[2];

    auto load_row = [&](int r, PF& p) {
        const int y = reflect_i(y_start + r, H_IMG);
        const size_t ro = (size_t)y * W_IMG;
        p.a0 = A[ro + c0];
        p.b0 = B[ro + c0];
        if (halo) { p.a1 = A[ro + c1]; p.b1 = B[ro + c1]; }
    };
    auto write_row = [&](int slot, const PF& p) {
        slab[slot][lane] = (f2){fast_sigmoid(p.a0), p.b0};
        if (halo) slab[slot][64 + lane] = (f2){fast_sigmoid(p.a1), p.b1};
    };

    // prologue: rows 0,1 staged; row 2 prefetched (written at iter 0)
    load_row(0, pf[0]);
    load_row(1, pf[1]);
    write_row(0, pf[0]);
    write_row(1, pf[1]);
    load_row(2, pf[0]);

    // group 0 (rows 0..10): guarded low edge
    group_iter<0, 11, 11, 11, true>(0, load_row, write_row, pf, slab, lane,
                                    vAB, vSQ, vX, loss_sum);
    // steady groups (rows 11..65): one shared instantiation, 5 trips
#pragma unroll 1
    for (int base = 11; base <= 55; base += 11)
        group_iter<0, 11, 11, 11, false>(base, load_row, write_row, pf, slab,
                                         lane, vAB, vSQ, vX, loss_sum);
    // tail (rows 66..73): writes rows 68..73 (NW=6), loads rows 69..73 (NL=5)
    group_iter<0, 8, 6, 5, false>(66, load_row, write_row, pf, slab, lane,
                                  vAB, vSQ, vX, loss_sum);

    // ---- reduction: wave shuffle -> LDS across 4 waves -> one atomic ----
#pragma unroll
    for (int off = 32; off > 0; off >>= 1)
        loss_sum += __shfl_down(loss_sum, off, 64);
    if (lane == 0) red[wv] = loss_sum;
    __syncthreads();
    if (tid == 0) {
        const float s = red[0] + red[1] + red[2] + red[3];
        atomicAdd(out, s * (1.0f / ((float)N_IMG * H_IMG * W_IMG)));
    }
}

extern "C" void kernel_launch(void* const* d_in, const int* in_sizes, int n_in,
                              void* d_out, int out_size, void* d_ws, size_t ws_size,
                              hipStream_t stream) {
    const float* inp = (const float*)d_in[0];
    const float* tgt = (const float*)d_in[1];
    float* out = (float*)d_out;

    // d_out is poisoned 0xAA before every launch; zero it for the atomic sum.
    hipMemsetAsync(out, 0, sizeof(float), stream);

    const int grid = (N_IMG * 16 * 16) / 4;  // 4096 wave-tasks / 4 waves = 1024
    ssim_main<<<grid, 256, 0, stream>>>(inp, tgt, out);
}

// Round 7
// 258.676 us; speedup vs baseline: 2.8412x; 2.8412x over previous
//
#include <hip/hip_runtime.h>
#include <math.h>

// SSIM-with-logits fused kernel for MI355X (gfx950). Round 7.
// Residency model (fits R2-R6): resident waves/SIMD = 512/(2*VGPR_Count) —
// the compiler mirrors an equal AGPR block and never spills-to-AGPR, so
// R4's 112-VGPR kernel is pinned at 2 waves/SIMD (8/CU). Its fat is the
// 44-reg global prefetch array. R7 deletes it with global_load_lds DMA:
//   raw A,B rows --DMA--> LDS slab (double-buffered 6-row chunks)
//   repack pass: sigmoid + build the PROVEN f2-interleaved ring (depth 12
//     -> chunk bases 0,6 mod 12: only two process templates)
//   process: R4's validated horizontal 11-tap + mod-ring vertical scatter
// Raw s_barrier asm (lgkmcnt(0) / vmcnt(0) only) instead of __syncthreads
// so the next chunk's DMA stays in flight across barriers.
// Target: true live state ~82 regs -> (256,3) spill-free -> 12 waves/CU.
// Canary: WRITE_SIZE (>1 MB means scratch spill; revert to R4 structure).

typedef __attribute__((ext_vector_type(2))) float f2;

#define H_IMG 1024
#define W_IMG 1024
#define N_IMG 16
#define TILE_W 256
#define TILE_H 32
#define PADR 5
#define RING_S 268   // f2 cells per ring row (266 used)
#define SLAB_S 268   // f32 cells per slab plane row (266 used)
#define NSLOT 12

// Normalized 1D Gaussian, WS=11, sigma=1.5 (absmax 0.0 in R1-R5)
constexpr float GW[11] = {
    0.00102838f, 0.00759877f, 0.03600077f, 0.10936069f, 0.21300553f,
    0.26601172f,
    0.21300553f, 0.10936069f, 0.03600077f, 0.00759877f, 0.00102838f};

__device__ __forceinline__ int reflect_i(int i, int n) {
    i = (i < 0) ? -i : i;
    i = (i >= n) ? (2 * n - 2 - i) : i;
    return i;
}

__device__ __forceinline__ float fast_sigmoid(float x) {
    return __builtin_amdgcn_rcpf(1.0f + __expf(-x));
}

__device__ __forceinline__ void ssim_emit(
    f2 mu, f2 sq, float e12, float& loss_sum)
{
    const float mu1 = mu.x, mu2 = mu.y;
    const float mu1s = mu1 * mu1;
    const float mu2s = mu2 * mu2;
    const float mu12 = mu1 * mu2;
    const float s1  = sq.x - mu1s;
    const float s2  = sq.y - mu2s;
    const float s12 = e12  - mu12;
    const float C1 = 1e-4f, C2 = 9e-4f;
    const float num = (2.0f * mu12 + C1) * (2.0f * s12 + C2);
    const float den = (mu1s + mu2s + C1) * (s1 + s2 + C2);
    float l = 1.0f - num * __builtin_amdgcn_rcpf(den);
    l = fminf(fmaxf(l, 0.0f), 1.0f) * 0.5f;
    loss_sum += l;
}

// async global->LDS DMA, 4 bytes/lane: dest = lds_base + lane*4
__device__ __forceinline__ void dma_f32(const float* gsrc, float* ldst) {
    __builtin_amdgcn_global_load_lds(
        (const __attribute__((address_space(1))) void*)gsrc,
        (__attribute__((address_space(3))) void*)ldst, 4, 0, 0);
}

// barriers WITHOUT the __syncthreads full-drain (keeps next DMA in flight)
#define BAR_VM()   asm volatile("s_waitcnt vmcnt(0)\n\ts_barrier" ::: "memory")
#define BAR_LGKM() asm volatile("s_waitcnt lgkmcnt(0)\n\ts_barrier" ::: "memory")

struct Ctx {
    const float* A;
    const float* B;
    float (*slab)[6][2][SLAB_S];   // [2][6][2][SLAB_S]
    f2 (*ring)[RING_S];            // [NSLOT][RING_S]
    int tid, lane, wv, c0, c1, y_start;
};

// Issue 24 DMAs for the 6-row chunk starting at base_row into slab[buf].
// Main: wave wv's lanes cover cells wv*64+lane (addresses = per-thread c0).
// Halo cells 256..265: every wave issues the same masked DMA (identical
// data, benign duplication) so vmcnt stays wave-uniform.
__device__ __forceinline__ void issue_dma6(const Ctx& cx, int base_row, int buf) {
#pragma unroll
    for (int i = 0; i < 6; ++i) {
        const int y = reflect_i(cx.y_start + base_row + i, H_IMG);
        const float* rowA = cx.A + ((size_t)y << 10);
        const float* rowB = cx.B + ((size_t)y << 10);
        dma_f32(rowA + cx.c0, &cx.slab[buf][i][0][cx.wv * 64]);
        dma_f32(rowB + cx.c0, &cx.slab[buf][i][1][cx.wv * 64]);
        if (cx.lane < 2 * PADR) {
            dma_f32(rowA + cx.c1, &cx.slab[buf][i][0][256]);
            dma_f32(rowB + cx.c1, &cx.slab[buf][i][1][256]);
        }
    }
}

// sigmoid + interleave slab chunk (rows B0..B0+5 mod 12) into the ring
template<int B0>
__device__ __forceinline__ void repack6(const Ctx& cx, int buf) {
#pragma unroll
    for (int i = 0; i < 6; ++i) {
        const int slot = (B0 + i) % NSLOT;
        const float a = cx.slab[buf][i][0][cx.tid];
        const float b = cx.slab[buf][i][1][cx.tid];
        cx.ring[slot][cx.tid] = (f2){fast_sigmoid(a), b};
        if (cx.tid < 2 * PADR) {
            const float a2 = cx.slab[buf][i][0][256 + cx.tid];
            const float b2 = cx.slab[buf][i][1][256 + cx.tid];
            cx.ring[slot][256 + cx.tid] = (f2){fast_sigmoid(a2), b2};
        }
    }
}

// Process 6 staged rows (labels RR=B0..B0+5 mod 12). Horizontal 11-tap +
// mod-12-ring vertical scatter; slot math validated bit-exact R2-R5
// (mod-11 variant), re-derived for depth 12: row r scatters into slots
// (r-j)%12 (j=0..10), output row r-10 completes -> emit slot (r+2)%12.
template<int B0, bool GUARD>
__device__ __forceinline__ void process6(
    const Ctx& cx, f2 (&vAB)[NSLOT], f2 (&vSQ)[NSLOT], float (&vX)[NSLOT],
    float& loss_sum)
{
#pragma unroll
    for (int i = 0; i < 6; ++i) {
        const int RR = B0 + i;   // 0..11 == row % 12 (exact row in GUARD chunks)
        f2 hAB = (f2)(0.0f), hSQ = (f2)(0.0f);
        float hab = 0.0f;
#pragma unroll
        for (int k = 0; k < 11; ++k) {
            const f2 v  = cx.ring[RR][cx.tid + k];
            const f2 w2 = ((f2)(GW[k])) * v;
            hAB += w2;
            hSQ  = __builtin_elementwise_fma(w2, v, hSQ);
            hab  = fmaf(w2.x, v.y, hab);
        }
#pragma unroll
        for (int j = 0; j < 11; ++j) {
            if (!(GUARD && j > RR)) {       // GUARD: skip negative output rows
                const int s = (RR - j + 24) % NSLOT;
                const f2 w = (f2)(GW[j]);
                vAB[s] = __builtin_elementwise_fma(w, hAB, vAB[s]);
                vSQ[s] = __builtin_elementwise_fma(w, hSQ, vSQ[s]);
                vX[s]  = fmaf(GW[j], hab, vX[s]);
            }
        }
        if (!GUARD || RR >= 10) {           // output row RR-10 complete
            const int s = (RR + 2) % NSLOT;
            ssim_emit(vAB[s], vSQ[s], vX[s], loss_sum);
            vAB[s] = (f2)(0.0f); vSQ[s] = (f2)(0.0f); vX[s] = 0.0f;
        }
    }
}

__global__ __launch_bounds__(256, 3) void ssim_main(
    const float* __restrict__ inp, const float* __restrict__ tgt,
    float* __restrict__ out)
{
    __shared__ float slab[2][6][2][SLAB_S];   // 25.7 KB raw staging
    __shared__ f2 ring[NSLOT][RING_S];        // 25.7 KB filtered ring
    __shared__ float red[4];

    const int tid  = threadIdx.x;
    const int lane = tid & 63;
    const int wv   = tid >> 6;

    const int blk = blockIdx.x;               // 2048 blocks
    const int img = blk >> 7;                 // 0..15
    const int rem = blk & 127;
    const int cxt = rem & 3;                  // column tile 0..3
    const int ry  = rem >> 2;                 // row band 0..31
    const int x0  = cxt * TILE_W;
    const int y0  = ry * TILE_H;

    const float* A = inp + (size_t)img * (H_IMG * (size_t)W_IMG);
    const float* B = tgt + (size_t)img * (H_IMG * (size_t)W_IMG);

    Ctx cx;
    cx.A = A; cx.B = B;
    cx.slab = slab; cx.ring = ring;
    cx.tid = tid; cx.lane = lane; cx.wv = wv;
    cx.c0 = reflect_i(x0 - PADR + tid, W_IMG);        // cell tid
    cx.c1 = reflect_i(x0 + 251 + lane, W_IMG);        // cell 256+lane
    cx.y_start = y0 - PADR;                           // 42 input rows: 7 chunks

    f2 vAB[NSLOT], vSQ[NSLOT];
    float vX[NSLOT];
#pragma unroll
    for (int j = 0; j < NSLOT; ++j) {
        vAB[j] = (f2)(0.0f); vSQ[j] = (f2)(0.0f); vX[j] = 0.0f;
    }
    float loss_sum = 0.0f;

    // chunk c covers rows 6c..6c+5; buf = c&1; DMA(c+1) issued after
    // repack(c) so at each step head only chunk c's DMAs are outstanding.
    issue_dma6(cx, 0, 0);

    // chunk 0 (rows 0..5, guarded edge)
    BAR_VM();  repack6<0>(cx, 0);  BAR_LGKM();
    issue_dma6(cx, 6, 1);
    process6<0, true>(cx, vAB, vSQ, vX, loss_sum);

    // chunk 1 (rows 6..11, guarded; row 11's guard is vacuous)
    BAR_VM();  repack6<6>(cx, 1);  BAR_LGKM();
    issue_dma6(cx, 12, 0);
    process6<6, true>(cx, vAB, vSQ, vX, loss_sum);

    // chunks 2..5 (rows 12..35)
#pragma unroll 1
    for (int cb = 12; cb <= 24; cb += 12) {
        BAR_VM();  repack6<0>(cx, 0);  BAR_LGKM();
        issue_dma6(cx, cb + 6, 1);
        process6<0, false>(cx, vAB, vSQ, vX, loss_sum);

        BAR_VM();  repack6<6>(cx, 1);  BAR_LGKM();
        issue_dma6(cx, cb + 12, 0);
        process6<6, false>(cx, vAB, vSQ, vX, loss_sum);
    }

    // chunk 6 (rows 36..41, last)
    BAR_VM();  repack6<0>(cx, 0);  BAR_LGKM();
    process6<0, false>(cx, vAB, vSQ, vX, loss_sum);

    // ---- reduction: wave shuffle -> LDS across 4 waves -> one atomic ----
    __syncthreads();
#pragma unroll
    for (int off = 32; off > 0; off >>= 1)
        loss_sum += __shfl_down(loss_sum, off, 64);
    if (lane == 0) red[wv] = loss_sum;
    __syncthreads();
    if (tid == 0) {
        const float s = red[0] + red[1] + red[2] + red[3];
        atomicAdd(out, s * (1.0f / ((float)N_IMG * H_IMG * W_IMG)));
    }
}

extern "C" void kernel_launch(void* const* d_in, const int* in_sizes, int n_in,
                              void* d_out, int out_size, void* d_ws, size_t ws_size,
                              hipStream_t stream) {
    const float* inp = (const float*)d_in[0];
    const float* tgt = (const float*)d_in[1];
    float* out = (float*)d_out;

    // d_out is poisoned 0xAA before every launch; zero it for the atomic sum.
    hipMemsetAsync(out, 0, sizeof(float), stream);

    const int grid = N_IMG * 4 * (H_IMG / TILE_H);  // 2048 blocks
    ssim_main<<<grid, 256, 0, stream>>>(inp, tgt, out);
}